// Round 13
// baseline (162.275 us; speedup 1.0000x reference)
//
#include <hip/hip_runtime.h>
#include <math.h>

// Problem constants (from reference setup_inputs)
#define BB 16
#define LL 64
#define FF 60
#define DD 256
#define UU 600
#define VV 10000
#define JMAX 10
#define MINL 4
#define EE 7           // MAX_LEN - MIN_LEN + 1
#define NEG (-1e9f)
#define TH 0.05f
#define BCAP 10240     // per-bucket record capacity (>= V)

// Workspace layout in u32/float units (ws_size ~256 MB per harness fill — ample).
#define UNT_OFF   0                         // unT[256][640]  (u padded 600->640)
#define WNT_OFF   163840                    // wnT[256][1024] (bl = b*64+l)
#define CNT_OFF   1040384                   // uint cnt[8] (written by k_prep blk 39)
#define SRT_OFF   1040392                   // records: 7 buckets x 10240 x 8 u32 (16B-aligned)
#define VAL_OFF   1613832                   // val[2][16][64][7]  (per v-half)
#define VOC_OFF   1628168                   // int voc[2][16][64][7]

// ---------------------------------------------------------------------------
// Fused prep: blocks [0,40) bucket-sort vocab records DETERMINISTICALLY
// (counting sort: pos(v) = #{v' < v with same vlen}); no atomics, bucket
// order = ascending v. Blocks [40,446) embed. Record (32B): w0..w4 = 10 x
// u16 LDS indices (u*13+j), w5 = v. Block 39 writes bucket totals to cnt[].
__global__ __launch_bounds__(256) void k_prep(const int* __restrict__ seg,
                                              const int* __restrict__ vlen,
                                              const float* __restrict__ x,
                                              const float* __restrict__ uf,
                                              const float* __restrict__ W,
                                              unsigned int* __restrict__ cnt,
                                              unsigned int* __restrict__ srt,
                                              float* __restrict__ unT,
                                              float* __restrict__ wnT) {
    __shared__ unsigned long long sP[4][2];  // per-wave packed prefix counts
    __shared__ int wTab[4][8];               // per-wave per-bucket counts (this block)
    __shared__ int sBase[8];                 // per-bucket counts below this block
    int blk = blockIdx.x;
    if (blk < 40) {
        int tid  = threadIdx.x;
        int lane = tid & 63;
        int w    = tid >> 6;
        int v    = blk * 256 + tid;

        // ---- prefix counts: scan vlen[0 .. blk*256), 16-bit packed lanes ----
        unsigned long long p0 = 0, p1 = 0;   // buckets 0-3 | 4-6, 16b fields
        int lim = blk * 256;
        for (int i = tid; i < lim; i += 256) {
            int e2 = vlen[i] - MINL;         // 0..6
            if (e2 < 4) p0 += 1ull << (e2 * 16);
            else        p1 += 1ull << ((e2 - 4) * 16);
        }
#pragma unroll
        for (int m = 32; m > 0; m >>= 1) {
            p0 += __shfl_xor(p0, m, 64);
            p1 += __shfl_xor(p1, m, 64);
        }
        if (lane == 0) { sP[w][0] = p0; sP[w][1] = p1; }

        // ---- own bucket + per-wave ballots (all lanes active; e=-1 invalid) ----
        int e = (v < VV) ? (vlen[v] - MINL) : -1;
        unsigned long long below = (lane == 0) ? 0ull : (~0ull >> (64 - lane));
        unsigned long long mym = 0;
#pragma unroll
        for (int b2 = 0; b2 < EE; ++b2) {
            unsigned long long m = __ballot(e == b2);
            if (lane == 0) wTab[w][b2] = (int)__popcll(m);
            if (e == b2) mym = m;
        }
        __syncthreads();
        if (tid < EE) {
            unsigned long long q0 = sP[0][0] + sP[1][0] + sP[2][0] + sP[3][0];
            unsigned long long q1 = sP[0][1] + sP[1][1] + sP[2][1] + sP[3][1];
            int base = (tid < 4) ? (int)((q0 >> (tid * 16)) & 0xffffull)
                                 : (int)((q1 >> ((tid - 4) * 16)) & 0xffffull);
            sBase[tid] = base;
            if (blk == 39)   // totals = prefix below blk 39 + blk 39's own
                cnt[tid] = (unsigned)(base + wTab[0][tid] + wTab[1][tid]
                                           + wTab[2][tid] + wTab[3][tid]);
        }
        __syncthreads();

        if (v < VV) {
            int prior = sBase[e];
#pragma unroll
            for (int w2 = 0; w2 < 4; ++w2) if (w2 < w) prior += wTab[w2][e];
            unsigned pos = (unsigned)(prior + (int)__popcll(mym & below));

            const int* s = seg + v * JMAX;
            unsigned int t[10];
#pragma unroll
            for (int j = 0; j < JMAX; ++j) t[j] = (unsigned int)(s[j] * 13 + j);
            unsigned int* dst = srt + ((size_t)e * BCAP + pos) * 8;
            uint4 qa, qb;
            qa.x = t[0] | (t[1] << 16);
            qa.y = t[2] | (t[3] << 16);
            qa.z = t[4] | (t[5] << 16);
            qa.w = t[6] | (t[7] << 16);
            qb.x = t[8] | (t[9] << 16);
            qb.y = (unsigned int)v;
            qb.z = 0; qb.w = 0;
            ((uint4*)dst)[0] = qa;
            ((uint4*)dst)[1] = qb;
        }
    } else {
        // embed: wave w of block handles row (blk-40)*4 + w; 1624 rows total.
        int w = threadIdx.x >> 6;
        int lane = threadIdx.x & 63;
        int id = (blk - 40) * 4 + w;
        const float* row;
        float* outB;
        int stride, col;
        if (id < UU) { row = uf + id * FF; outB = unT; stride = 640;  col = id; }
        else { int bl = id - UU; row = x + bl * FF; outB = wnT; stride = 1024; col = bl; }

        float r0 = 0.f, r1 = 0.f, r2 = 0.f, r3 = 0.f;
#pragma unroll 4
        for (int f = 0; f < FF; ++f) {
            float xv = row[f];  // wave-uniform broadcast load
            r0 += xv * W[f * DD + lane];
            r1 += xv * W[f * DD + lane + 64];
            r2 += xv * W[f * DD + lane + 128];
            r3 += xv * W[f * DD + lane + 192];
        }
        float ss = r0 * r0 + r1 * r1 + r2 * r2 + r3 * r3;
#pragma unroll
        for (int m = 32; m > 0; m >>= 1) ss += __shfl_xor(ss, m, 64);
        float inv = 1.0f / (sqrtf(ss) + 1e-8f);   // matches ref x/(norm+1e-8)
        outB[(lane      ) * stride + col] = r0 * inv;
        outB[(lane +  64) * stride + col] = r1 * inv;
        outB[(lane + 128) * stride + col] = r2 * inv;
        outB[(lane + 192) * stride + col] = r3 * inv;
    }
}

// ---------------------------------------------------------------------------
// Per-wave segment pass, STATIC K, 4 l-positions per record — r6 body
// verbatim. RAW-sum compare + min-v tie, winner normalized once at the
// reduce; ascending-v buckets keep ref's first-index tie semantics.
template<int K>
__device__ __forceinline__ void seg_pass4(const unsigned int* __restrict__ srt,
                                          const float* __restrict__ lds,
                                          int e, int r0, int r1, int lane, int wave,
                                          float (*redS)[8], int (*redV)[8]) {
    float s0 = -1e30f, s1 = -1e30f, s2 = -1e30f, s3 = -1e30f;
    int w0 = VV, w1 = VV, w2 = VV, w3 = VV;
    for (int p = r0 + lane; p < r1; p += 64) {
        const uint4* pp = (const uint4*)(srt + ((size_t)e * BCAP + p) * 8);
        uint4 qa = pp[0];
        uint4 qb = pp[1];
        unsigned int tw[5] = {qa.x, qa.y, qa.z, qa.w, qb.x};
        int v = (int)qb.y;
        float a0 = 0.f, a1 = 0.f, a2 = 0.f, a3 = 0.f;
#pragma unroll
        for (int j = 0; j < K; ++j) {
            int idx = (int)((tw[j >> 1] >> ((j & 1) * 16)) & 0xffffu);
            a0 += lds[idx];
            a1 += lds[idx + 1];
            a2 += lds[idx + 2];
            a3 += lds[idx + 3];
        }
        bool p0 = (a0 > s0) || (a0 == s0 && v < w0);
        bool p1 = (a1 > s1) || (a1 == s1 && v < w1);
        bool p2 = (a2 > s2) || (a2 == s2 && v < w2);
        bool p3 = (a3 > s3) || (a3 == s3 && v < w3);
        s0 = p0 ? a0 : s0;  w0 = p0 ? v : w0;
        s1 = p1 ? a1 : s1;  w1 = p1 ? v : w1;
        s2 = p2 ? a2 : s2;  w2 = p2 ? v : w2;
        s3 = p3 ? a3 : s3;  w3 = p3 ? v : w3;
    }
#pragma unroll
    for (int off = 32; off > 0; off >>= 1) {
        float os; int ov;
        os = __shfl_down(s0, off, 64); ov = __shfl_down(w0, off, 64);
        if (os > s0 || (os == s0 && ov < w0)) { s0 = os; w0 = ov; }
        os = __shfl_down(s1, off, 64); ov = __shfl_down(w1, off, 64);
        if (os > s1 || (os == s1 && ov < w1)) { s1 = os; w1 = ov; }
        os = __shfl_down(s2, off, 64); ov = __shfl_down(w2, off, 64);
        if (os > s2 || (os == s2 && ov < w2)) { s2 = os; w2 = ov; }
        os = __shfl_down(s3, off, 64); ov = __shfl_down(w3, off, 64);
        if (os > s3 || (os == s3 && ov < w3)) { s3 = os; w3 = ov; }
    }
    if (lane == 0) {
        redS[e * 4 + 0][wave] = s0; redV[e * 4 + 0][wave] = w0;
        redS[e * 4 + 1][wave] = s1; redV[e * 4 + 1][wave] = w1;
        redS[e * 4 + 2][wave] = s2; redV[e * 4 + 2][wave] = w2;
        redS[e * 4 + 3][wave] = s3; redV[e * 4 + 3][wave] = w3;
    }
}

// ---------------------------------------------------------------------------
// FUSED sim+score (r10 done right): 512 blocks = (quad l0-major, half low
// bit), 512 threads. The tile is COMPUTED in-block instead of read from a
// sim round-trip — but unlike r10: (1) the 13x256 wn panel is staged into a
// SEPARATE LDS buffer once (broadcast-read thereafter; r10 issued 3328
// serialized uniform GLOBAL loads per thread — the 149us disaster), (2) 13
// register accumulators under a (512,2) VGPR cap (no spill), (3) results
// written to the separate tile buffer (no overwrite hazard). d=0..255
// accumulation order bit-identical to the old k_sim. Rows >= LL zeroed via
// the wn stage guard (also prevents wnT column overrun at b=15). Rows in
// [len,64) now hold real values instead of poison — they feed only
// non-viable slots, which write NEG regardless. Scan phase = r12 verbatim.
__global__ __launch_bounds__(512, 2) void k_simscore(const float* __restrict__ unT,
                                                     const float* __restrict__ wnT,
                                                     const unsigned int* __restrict__ srt,
                                                     const unsigned int* __restrict__ cnt,
                                                     const int* __restrict__ lengths,
                                                     float* __restrict__ val,
                                                     int* __restrict__ voc) {
    __shared__ float tile[UU * 13];   // 31.2 KB  [u][13] sim tile
    __shared__ float wn[DD * 13];     // 13.3 KB  [d][13] wn panel
    __shared__ float redS[28][8];     // [e*4+dl][wave]
    __shared__ int   redV[28][8];

    int blk  = blockIdx.x;
    int half = blk & 1;              // low bit: halves of a quad adjacent
    int q    = blk >> 1;             // 0..255, l0-major
    int b    = q & 15;
    int l0   = (q >> 4) * 4;
    int tid  = threadIdx.x;
    int len  = lengths[b];           // uniform scalar load

    if (l0 + MINL - 1 >= len) {      // no bucket active for this quad
        if (tid < 28) {
            int e  = tid >> 2;
            int dl = tid & 3;
            int o = (half * BB * LL + b * 64 + l0 + dl) * EE + e;
            val[o] = NEG;
            voc[o] = 0;
        }
        return;                       // block-uniform: no barrier hazards
    }

    if (tid < 224) {                 // init all 28x8 reduction slots
        redS[tid >> 3][tid & 7] = -1e30f;
        redV[tid >> 3][tid & 7] = VV;
    }

    // ---- Stage wn panel: wn[d*13+r] = wnT[d][bl0+r], zero for l0+r >= 64 ----
    {
        int bl0 = b * 64 + l0;
        for (int i = tid; i < DD * 13; i += 512) {
            int d = i / 13;
            int r = i - d * 13;
            wn[i] = (l0 + r < LL) ? wnT[d * 1024 + bl0 + r] : 0.0f;
        }
    }
    __syncthreads();

    // ---- Compute tile: for each u, 13 dots over d (order = old k_sim) ----
    // Pass A: u = tid (all 512). Pass B: u = 512+tid (tid < 88).
    {
        float acc[13];
#pragma unroll
        for (int r = 0; r < 13; ++r) acc[r] = 0.0f;
        for (int d = 0; d < DD; ++d) {
            float uv = unT[d * 640 + tid];          // coalesced
            const float* wrow = wn + d * 13;        // LDS broadcast
#pragma unroll
            for (int r = 0; r < 13; ++r) acc[r] += uv * wrow[r];
        }
#pragma unroll
        for (int r = 0; r < 13; ++r) tile[tid * 13 + r] = acc[r];

        if (tid < UU - 512) {                       // 88 threads: second u
            int u2 = 512 + tid;
#pragma unroll
            for (int r = 0; r < 13; ++r) acc[r] = 0.0f;
            for (int d = 0; d < DD; ++d) {
                float uv = unT[d * 640 + u2];
                const float* wrow = wn + d * 13;
#pragma unroll
                for (int r = 0; r < 13; ++r) acc[r] += uv * wrow[r];
            }
#pragma unroll
            for (int r = 0; r < 13; ++r) tile[u2 * 13 + r] = acc[r];
        }
    }
    __syncthreads();

    int wave = tid >> 6, lane = tid & 63;

    // Work-proportional wave slicing over this half's ACTIVE buckets.
    unsigned nlo[EE], nhi[EE], Bw[EE];
    unsigned Wtot = 0;
#pragma unroll
    for (int e = 0; e < EE; ++e) {
        unsigned n = cnt[e];
        unsigned lo = half ? (n >> 1) : 0;
        unsigned hi = half ? n : (n >> 1);
        if (l0 + e + MINL - 1 >= len) { lo = 0; hi = 0; }  // bucket dead for whole quad
        nlo[e] = lo; nhi[e] = hi;
        Bw[e] = Wtot;
        Wtot += (hi - lo) * (unsigned)(e + MINL);
    }
    unsigned qlo = (unsigned)(((unsigned long long)Wtot * (unsigned)wave) >> 3);
    unsigned qhi = (unsigned)(((unsigned long long)Wtot * (unsigned)(wave + 1)) >> 3);

#pragma unroll
    for (int e = 0; e < EE; ++e) {
        unsigned K = (unsigned)(e + MINL);
        unsigned segw = (nhi[e] - nlo[e]) * K;
        unsigned Be = Bw[e];
        if (qhi <= Be || qlo >= Be + segw || segw == 0) continue;
        unsigned a = (qlo > Be) ? (qlo - Be) : 0;
        unsigned bb = qhi - Be; if (bb > segw) bb = segw;
        int r0 = (int)(nlo[e] + (a + K - 1) / K);
        int r1 = (int)(nlo[e] + (bb + K - 1) / K);
        if (r1 <= r0) continue;
        switch (e) {   // wave-uniform branch
            case 0: seg_pass4<4> (srt, tile, 0, r0, r1, lane, wave, redS, redV); break;
            case 1: seg_pass4<5> (srt, tile, 1, r0, r1, lane, wave, redS, redV); break;
            case 2: seg_pass4<6> (srt, tile, 2, r0, r1, lane, wave, redS, redV); break;
            case 3: seg_pass4<7> (srt, tile, 3, r0, r1, lane, wave, redS, redV); break;
            case 4: seg_pass4<8> (srt, tile, 4, r0, r1, lane, wave, redS, redV); break;
            case 5: seg_pass4<9> (srt, tile, 5, r0, r1, lane, wave, redS, redV); break;
            case 6: seg_pass4<10>(srt, tile, 6, r0, r1, lane, wave, redS, redV); break;
        }
    }
    __syncthreads();

    if (tid < 28) {   // reduce 8 wave-slots per (e, dl); normalize winner only
        int e  = tid >> 2;
        int dl = tid & 3;
        float s = redS[tid][0];
        int  vv = redV[tid][0];
#pragma unroll
        for (int w2 = 1; w2 < 8; ++w2) {
            float os = redS[tid][w2];
            int   ov = redV[tid][w2];
            if (os > s || (os == s && ov < vv)) { s = os; vv = ov; }
        }
        int lg = l0 + dl;
        int k = e + MINL;
        bool viable = (lg + k - 1) < len;
        float sn = s / (float)k;   // bit-same as ref a/k for the winner
        int o = (half * BB * LL + b * 64 + lg) * EE + e;
        val[o] = viable ? sn : NEG;
        voc[o] = viable ? vv : 0;  // ref argmax of all-NEG = 0
    }
}

// ---------------------------------------------------------------------------
// Per-b: merge the two v-halves slot-wise (tie -> smaller voc = smaller v),
// then flat argmax over the 448 (l,e) slots (min flat index on ties),
// any_matched = merged max > THRESH. Outputs written as float32 values.
__global__ __launch_bounds__(512) void k_final(const float* __restrict__ val,
                                               const int* __restrict__ voc,
                                               float* __restrict__ out) {
    __shared__ float sS[8];
    __shared__ int   sI[8];
    __shared__ int   sV[8];
    __shared__ int   sA[8];
    int b = blockIdx.x;
    int t = threadIdx.x;
    float s = -3e38f;
    int idx = 1 << 30;
    int vc = 0;
    int any = 0;
    if (t < LL * EE) {
        int o0 = b * LL * EE + t;
        int o1 = BB * LL * EE + o0;
        float s0 = val[o0], s1 = val[o1];
        int   v0 = voc[o0], v1 = voc[o1];
        bool sel = (s1 > s0) || (s1 == s0 && v1 < v0);
        s  = sel ? s1 : s0;
        vc = sel ? v1 : v0;
        idx = t;
        any = (s > TH) ? 1 : 0;
    }
#pragma unroll
    for (int off = 32; off > 0; off >>= 1) {
        float os = __shfl_down(s, off, 64);
        int   oi = __shfl_down(idx, off, 64);
        int   ov = __shfl_down(vc, off, 64);
        int   oa = __shfl_down(any, off, 64);
        if (os > s || (os == s && oi < idx)) { s = os; idx = oi; vc = ov; }
        any |= oa;
    }
    int w = t >> 6, lane = t & 63;
    if (lane == 0) { sS[w] = s; sI[w] = idx; sV[w] = vc; sA[w] = any; }
    __syncthreads();
    if (t == 0) {
        for (int w2 = 1; w2 < 8; ++w2) {
            float os = sS[w2];
            int   oi = sI[w2];
            if (os > s || (os == s && oi < idx)) { s = os; idx = oi; vc = sV[w2]; }
            any |= sA[w2];
        }
        int start = idx / EE;
        int e = idx - start * EE;
        int end = e + start + MINL - 1;
        out[b]      = s;
        out[16 + b] = (float)start;
        out[32 + b] = (float)end;
        out[48 + b] = any ? 1.0f : 0.0f;
        out[64 + b] = (float)vc;
    }
}

// ---------------------------------------------------------------------------
extern "C" void kernel_launch(void* const* d_in, const int* in_sizes, int n_in,
                              void* d_out, int out_size, void* d_ws, size_t ws_size,
                              hipStream_t stream) {
    const float* x       = (const float*)d_in[0];   // [16][64][60]
    const float* uf      = (const float*)d_in[1];   // [600][60]
    const float* W       = (const float*)d_in[2];   // [60][256]
    const int*   lengths = (const int*)d_in[3];     // [16]
    const int*   seg     = (const int*)d_in[4];     // [10000][10]
    const int*   vlen    = (const int*)d_in[5];     // [10000]
    float* out = (float*)d_out;
    float* ws  = (float*)d_ws;

    float*        unT = ws + UNT_OFF;
    float*        wnT = ws + WNT_OFF;
    unsigned int* cnt = (unsigned int*)(ws + CNT_OFF);
    unsigned int* srt = (unsigned int*)(ws + SRT_OFF);
    float*        val = ws + VAL_OFF;
    int*          voc = (int*)(ws + VOC_OFF);

    // 3 dispatches: prep -> fused sim+score -> final.
    k_prep<<<446, 256, 0, stream>>>(seg, vlen, x, uf, W, cnt, srt, unT, wnT);
    k_simscore<<<512, 512, 0, stream>>>(unT, wnT, srt, cnt, lengths, val, voc);
    k_final<<<BB, 512, 0, stream>>>(val, voc, out);
}

// Round 15
// 129.345 us; speedup vs baseline: 1.2546x; 1.2546x over previous
//
#include <hip/hip_runtime.h>
#include <math.h>

// Problem constants (from reference setup_inputs)
#define BB 16
#define LL 64
#define FF 60
#define DD 256
#define UU 600
#define VV 10000
#define JMAX 10
#define MINL 4
#define EE 7           // MAX_LEN - MIN_LEN + 1
#define NEG (-1e9f)
#define TH 0.05f
#define BCAP 10240     // per-bucket record capacity (>= V)

// Workspace layout in u32/float units (ws_size ~256 MB per harness fill — ample).
#define UNT_OFF   0                         // unT[256][640]  (u padded 600->640)
#define WNT_OFF   163840                    // wnT[256][1024] (bl = b*64+l)
#define SIM_OFF   425984                    // sim[16][64][600]
#define CNT_OFF   1040384                   // uint cnt[8] (written by k_prep blk 39)
#define SRT_OFF   1040392                   // records: 7 buckets x 10240 x 8 u32 (16B-aligned)
#define BEST_OFF  1613832                   // u64 best[16] (u32-offset even => 8B aligned)
#define DONE_OFF  1613864                   // uint done

// ---------------------------------------------------------------------------
// Fused prep: blocks [0,40) bucket-sort vocab records DETERMINISTICALLY
// (counting sort: pos(v) = #{v' < v with same vlen}); no atomics, bucket
// order = ascending v. Blocks [40,446) embed. Record (32B): w0..w4 = 10 x
// u16 LDS indices (u*13+j), w5 = v. Block 39 writes bucket totals to cnt[]
// and zeroes best[]/done (plain stores; kernel boundary makes them visible).
__global__ __launch_bounds__(256) void k_prep(const int* __restrict__ seg,
                                              const int* __restrict__ vlen,
                                              const float* __restrict__ x,
                                              const float* __restrict__ uf,
                                              const float* __restrict__ W,
                                              unsigned int* __restrict__ cnt,
                                              unsigned int* __restrict__ srt,
                                              float* __restrict__ unT,
                                              float* __restrict__ wnT,
                                              unsigned long long* __restrict__ best,
                                              unsigned int* __restrict__ done) {
    __shared__ unsigned long long sP[4][2];  // per-wave packed prefix counts
    __shared__ int wTab[4][8];               // per-wave per-bucket counts (this block)
    __shared__ int sBase[8];                 // per-bucket counts below this block
    int blk = blockIdx.x;
    if (blk < 40) {
        int tid  = threadIdx.x;
        int lane = tid & 63;
        int w    = tid >> 6;
        int v    = blk * 256 + tid;

        // ---- prefix counts: scan vlen[0 .. blk*256), 16-bit packed lanes ----
        unsigned long long p0 = 0, p1 = 0;   // buckets 0-3 | 4-6, 16b fields
        int lim = blk * 256;
        for (int i = tid; i < lim; i += 256) {
            int e2 = vlen[i] - MINL;         // 0..6
            if (e2 < 4) p0 += 1ull << (e2 * 16);
            else        p1 += 1ull << ((e2 - 4) * 16);
        }
#pragma unroll
        for (int m = 32; m > 0; m >>= 1) {
            p0 += __shfl_xor(p0, m, 64);
            p1 += __shfl_xor(p1, m, 64);
        }
        if (lane == 0) { sP[w][0] = p0; sP[w][1] = p1; }

        // ---- own bucket + per-wave ballots (all lanes active; e=-1 invalid) ----
        int e = (v < VV) ? (vlen[v] - MINL) : -1;
        unsigned long long below = (lane == 0) ? 0ull : (~0ull >> (64 - lane));
        unsigned long long mym = 0;
#pragma unroll
        for (int b2 = 0; b2 < EE; ++b2) {
            unsigned long long m = __ballot(e == b2);
            if (lane == 0) wTab[w][b2] = (int)__popcll(m);
            if (e == b2) mym = m;
        }
        __syncthreads();
        if (tid < EE) {
            unsigned long long q0 = sP[0][0] + sP[1][0] + sP[2][0] + sP[3][0];
            unsigned long long q1 = sP[0][1] + sP[1][1] + sP[2][1] + sP[3][1];
            int base = (tid < 4) ? (int)((q0 >> (tid * 16)) & 0xffffull)
                                 : (int)((q1 >> ((tid - 4) * 16)) & 0xffffull);
            sBase[tid] = base;
            if (blk == 39)   // totals = prefix below blk 39 + blk 39's own
                cnt[tid] = (unsigned)(base + wTab[0][tid] + wTab[1][tid]
                                           + wTab[2][tid] + wTab[3][tid]);
        }
        if (blk == 39) {     // zero the k_score atomic state for this launch
            if (tid >= 128 && tid < 144) best[tid - 128] = 0ull;
            if (tid == 144) *done = 0u;
        }
        __syncthreads();

        if (v < VV) {
            int prior = sBase[e];
#pragma unroll
            for (int w2 = 0; w2 < 4; ++w2) if (w2 < w) prior += wTab[w2][e];
            unsigned pos = (unsigned)(prior + (int)__popcll(mym & below));

            const int* s = seg + v * JMAX;
            unsigned int t[10];
#pragma unroll
            for (int j = 0; j < JMAX; ++j) t[j] = (unsigned int)(s[j] * 13 + j);
            unsigned int* dst = srt + ((size_t)e * BCAP + pos) * 8;
            uint4 qa, qb;
            qa.x = t[0] | (t[1] << 16);
            qa.y = t[2] | (t[3] << 16);
            qa.z = t[4] | (t[5] << 16);
            qa.w = t[6] | (t[7] << 16);
            qb.x = t[8] | (t[9] << 16);
            qb.y = (unsigned int)v;
            qb.z = 0; qb.w = 0;
            ((uint4*)dst)[0] = qa;
            ((uint4*)dst)[1] = qb;
        }
    } else {
        // embed: wave w of block handles row (blk-40)*4 + w; 1624 rows total.
        int w = threadIdx.x >> 6;
        int lane = threadIdx.x & 63;
        int id = (blk - 40) * 4 + w;
        const float* row;
        float* outB;
        int stride, col;
        if (id < UU) { row = uf + id * FF; outB = unT; stride = 640;  col = id; }
        else { int bl = id - UU; row = x + bl * FF; outB = wnT; stride = 1024; col = bl; }

        float r0 = 0.f, r1 = 0.f, r2 = 0.f, r3 = 0.f;
#pragma unroll 4
        for (int f = 0; f < FF; ++f) {
            float xv = row[f];  // wave-uniform broadcast load
            r0 += xv * W[f * DD + lane];
            r1 += xv * W[f * DD + lane + 64];
            r2 += xv * W[f * DD + lane + 128];
            r3 += xv * W[f * DD + lane + 192];
        }
        float ss = r0 * r0 + r1 * r1 + r2 * r2 + r3 * r3;
#pragma unroll
        for (int m = 32; m > 0; m >>= 1) ss += __shfl_xor(ss, m, 64);
        float inv = 1.0f / (sqrtf(ss) + 1e-8f);   // matches ref x/(norm+1e-8)
        outB[(lane      ) * stride + col] = r0 * inv;
        outB[(lane +  64) * stride + col] = r1 * inv;
        outB[(lane + 128) * stride + col] = r2 * inv;
        outB[(lane + 192) * stride + col] = r3 * inv;
    }
}

// ---------------------------------------------------------------------------
// sim[b][l][u] = wn[bl] . un[u].  512 blocks = (b, l-quad, u-half), 320
// threads. Thread tile: 4l x 1u; wn read as wave-uniform float4 per d.
__global__ __launch_bounds__(320) void k_sim(const float* __restrict__ unT,
                                             const float* __restrict__ wnT,
                                             const int* __restrict__ lengths,
                                             float* __restrict__ sim) {
    int blk = blockIdx.x;
    int b  = blk >> 5;
    int r  = blk & 31;
    int l0 = (r >> 1) * 4;
    if (l0 >= lengths[b]) return;       // rows beyond sentence length unused
    int uh = r & 1;
    int bl0 = b * 64 + l0;
    int u = uh * 320 + threadIdx.x;     // < 640 (unT padded; stores guarded)

    float a0 = 0.f, a1 = 0.f, a2 = 0.f, a3 = 0.f;
#pragma unroll 8
    for (int d = 0; d < DD; ++d) {
        float4 wv = *(const float4*)(wnT + d * 1024 + bl0);  // uniform 16B
        float v  = unT[d * 640 + u];
        a0 += wv.x * v;
        a1 += wv.y * v;
        a2 += wv.z * v;
        a3 += wv.w * v;
    }
    if (u < UU) {
        sim[(bl0 + 0) * UU + u] = a0;
        sim[(bl0 + 1) * UU + u] = a1;
        sim[(bl0 + 2) * UU + u] = a2;
        sim[(bl0 + 3) * UU + u] = a3;
    }
}

// ---------------------------------------------------------------------------
// Per-wave segment pass, STATIC K, 4 l-positions per record — r6 body
// verbatim. RAW-sum compare + min-v tie, winner normalized once at the
// reduce; ascending-v buckets keep ref's first-index tie semantics.
template<int K>
__device__ __forceinline__ void seg_pass4(const unsigned int* __restrict__ srt,
                                          const float* __restrict__ lds,
                                          int e, int r0, int r1, int lane, int wave,
                                          float (*redS)[8], int (*redV)[8]) {
    float s0 = -1e30f, s1 = -1e30f, s2 = -1e30f, s3 = -1e30f;
    int w0 = VV, w1 = VV, w2 = VV, w3 = VV;
    for (int p = r0 + lane; p < r1; p += 64) {
        const uint4* pp = (const uint4*)(srt + ((size_t)e * BCAP + p) * 8);
        uint4 qa = pp[0];
        uint4 qb = pp[1];
        unsigned int tw[5] = {qa.x, qa.y, qa.z, qa.w, qb.x};
        int v = (int)qb.y;
        float a0 = 0.f, a1 = 0.f, a2 = 0.f, a3 = 0.f;
#pragma unroll
        for (int j = 0; j < K; ++j) {
            int idx = (int)((tw[j >> 1] >> ((j & 1) * 16)) & 0xffffu);
            a0 += lds[idx];
            a1 += lds[idx + 1];
            a2 += lds[idx + 2];
            a3 += lds[idx + 3];
        }
        bool p0 = (a0 > s0) || (a0 == s0 && v < w0);
        bool p1 = (a1 > s1) || (a1 == s1 && v < w1);
        bool p2 = (a2 > s2) || (a2 == s2 && v < w2);
        bool p3 = (a3 > s3) || (a3 == s3 && v < w3);
        s0 = p0 ? a0 : s0;  w0 = p0 ? v : w0;
        s1 = p1 ? a1 : s1;  w1 = p1 ? v : w1;
        s2 = p2 ? a2 : s2;  w2 = p2 ? v : w2;
        s3 = p3 ? a3 : s3;  w3 = p3 ? v : w3;
    }
#pragma unroll
    for (int off = 32; off > 0; off >>= 1) {
        float os; int ov;
        os = __shfl_down(s0, off, 64); ov = __shfl_down(w0, off, 64);
        if (os > s0 || (os == s0 && ov < w0)) { s0 = os; w0 = ov; }
        os = __shfl_down(s1, off, 64); ov = __shfl_down(w1, off, 64);
        if (os > s1 || (os == s1 && ov < w1)) { s1 = os; w1 = ov; }
        os = __shfl_down(s2, off, 64); ov = __shfl_down(w2, off, 64);
        if (os > s2 || (os == s2 && ov < w2)) { s2 = os; w2 = ov; }
        os = __shfl_down(s3, off, 64); ov = __shfl_down(w3, off, 64);
        if (os > s3 || (os == s3 && ov < w3)) { s3 = os; w3 = ov; }
    }
    if (lane == 0) {
        redS[e * 4 + 0][wave] = s0; redV[e * 4 + 0][wave] = w0;
        redS[e * 4 + 1][wave] = s1; redV[e * 4 + 1][wave] = w1;
        redS[e * 4 + 2][wave] = s2; redV[e * 4 + 2][wave] = w2;
        redS[e * 4 + 3][wave] = s3; redV[e * 4 + 3][wave] = w3;
    }
}

// ---------------------------------------------------------------------------
// Phase 3: 512 blocks = (v-half, b, l-quad), 512 threads — r11 staging/scan
// verbatim. ENDING CHANGED: instead of val/voc + a k_final dispatch, each
// live block packs its 28 slot-winners into u64 keys (enc(score)|511-idx|
// 16383-voc: lexicographic max == ref's slot-merge + flat-argmax + min-v
// ties), wave-0-reduces, and atomicMax's into best[b]. A done-counter
// elects the LAST block to decode all 16 b's and write out. All cross-
// block traffic is device-scope atomics (r1's outputs 0-3 passing through
// this exact protocol exonerated it; the r1-r3 voc bug was stale plain-
// store srt across gg.sync — impossible here across kernel boundaries).
__global__ __launch_bounds__(512, 2) void k_score(const float* __restrict__ sim,
                                                  const unsigned int* __restrict__ srt,
                                                  const unsigned int* __restrict__ cnt,
                                                  const int* __restrict__ lengths,
                                                  unsigned long long* __restrict__ best,
                                                  unsigned int* __restrict__ done,
                                                  float* __restrict__ out) {
    __shared__ float lds[UU * 13];   // 31.2 KB
    __shared__ float redS[28][8];    // [e*4+dl][wave]
    __shared__ int   redV[28][8];
    __shared__ int   isLast;

    int blk = blockIdx.x;
    int half = blk >> 8;
    int rest = blk & 255;
    int b  = rest >> 4;
    int l0 = (rest & 15) * 4;
    int tid = threadIdx.x;
    int len = lengths[b];            // uniform scalar load
    bool alive = (l0 + MINL - 1 < len);   // block-uniform

    if (alive) {
        if (tid < 224) {                 // init all 28x8 reduction slots
            redS[tid >> 3][tid & 7] = -1e30f;
            redV[tid >> 3][tid & 7] = VV;
        }
        // Stage sim tile -> LDS transposed, float4-vectorized: 13 rows x 150
        // float4 chunks; (b*64+m)*600 + 4c is 16B-aligned (600 % 4 == 0).
        for (int i = tid; i < 13 * 150; i += 512) {
            int r = i / 150;
            int c = i - r * 150;
            int m = l0 + r;
            float4 v4;
            if (m < LL) v4 = *(const float4*)(sim + (size_t)(b * 64 + m) * UU + 4 * c);
            else        v4 = make_float4(0.f, 0.f, 0.f, 0.f);
            int u0 = 4 * c;
            lds[(u0 + 0) * 13 + r] = v4.x;
            lds[(u0 + 1) * 13 + r] = v4.y;
            lds[(u0 + 2) * 13 + r] = v4.z;
            lds[(u0 + 3) * 13 + r] = v4.w;
        }
        __syncthreads();

        int wave = tid >> 6, lane = tid & 63;

        // Work-proportional wave slicing over this half's ACTIVE buckets.
        unsigned nlo[EE], nhi[EE], Bw[EE];
        unsigned Wtot = 0;
#pragma unroll
        for (int e = 0; e < EE; ++e) {
            unsigned n = cnt[e];
            unsigned lo = half ? (n >> 1) : 0;
            unsigned hi = half ? n : (n >> 1);
            if (l0 + e + MINL - 1 >= len) { lo = 0; hi = 0; }  // bucket dead
            nlo[e] = lo; nhi[e] = hi;
            Bw[e] = Wtot;
            Wtot += (hi - lo) * (unsigned)(e + MINL);
        }
        unsigned qlo = (unsigned)(((unsigned long long)Wtot * (unsigned)wave) >> 3);
        unsigned qhi = (unsigned)(((unsigned long long)Wtot * (unsigned)(wave + 1)) >> 3);

#pragma unroll
        for (int e = 0; e < EE; ++e) {
            unsigned K = (unsigned)(e + MINL);
            unsigned segw = (nhi[e] - nlo[e]) * K;
            unsigned Be = Bw[e];
            if (qhi <= Be || qlo >= Be + segw || segw == 0) continue;
            unsigned a = (qlo > Be) ? (qlo - Be) : 0;
            unsigned bb = qhi - Be; if (bb > segw) bb = segw;
            int r0 = (int)(nlo[e] + (a + K - 1) / K);
            int r1 = (int)(nlo[e] + (bb + K - 1) / K);
            if (r1 <= r0) continue;
            switch (e) {   // wave-uniform branch
                case 0: seg_pass4<4> (srt, lds, 0, r0, r1, lane, wave, redS, redV); break;
                case 1: seg_pass4<5> (srt, lds, 1, r0, r1, lane, wave, redS, redV); break;
                case 2: seg_pass4<6> (srt, lds, 2, r0, r1, lane, wave, redS, redV); break;
                case 3: seg_pass4<7> (srt, lds, 3, r0, r1, lane, wave, redS, redV); break;
                case 4: seg_pass4<8> (srt, lds, 4, r0, r1, lane, wave, redS, redV); break;
                case 5: seg_pass4<9> (srt, lds, 5, r0, r1, lane, wave, redS, redV); break;
                case 6: seg_pass4<10>(srt, lds, 6, r0, r1, lane, wave, redS, redV); break;
            }
        }
        __syncthreads();

        // Build packed candidate keys and atomicMax into best[b].
        unsigned long long key = 0ull;
        if (tid < 28) {
            int e  = tid >> 2;
            int dl = tid & 3;
            float s = redS[tid][0];
            int  vv = redV[tid][0];
#pragma unroll
            for (int w2 = 1; w2 < 8; ++w2) {
                float os = redS[tid][w2];
                int   ov = redV[tid][w2];
                if (os > s || (os == s && ov < vv)) { s = os; vv = ov; }
            }
            int lg = l0 + dl;
            int k = e + MINL;
            if (lg + k - 1 < len) {          // only viable slots contribute
                float sn = s / (float)k;     // bit-same as ref a/k for winner
                sn += 0.0f;                  // canonicalize -0 -> +0
                unsigned int ub  = __float_as_uint(sn);
                unsigned int enc = (ub & 0x80000000u) ? ~ub : (ub | 0x80000000u);
                int idx = lg * EE + e;       // flat (l,e) index, < 448
                key = ((unsigned long long)enc << 32)
                    | ((unsigned long long)(unsigned)(511 - idx) << 14)
                    | (unsigned long long)(unsigned)(16383 - vv);
            }
        }
        if (tid < 64) {   // wave-0 reduce (lanes 28..63 hold key=0)
#pragma unroll
            for (int off = 32; off > 0; off >>= 1) {
                unsigned long long ok = __shfl_down(key, off, 64);
                if (ok > key) key = ok;
            }
            if (tid == 0 && key != 0ull) atomicMax(&best[b], key);
        }
    }

    // ---- done-counter: last of the 512 blocks decodes and writes out ----
    if (tid == 0) {
        __threadfence();                       // release our atomicMax
        unsigned int old = atomicAdd(done, 1u);
        isLast = (old == 511u) ? 1 : 0;
    }
    __syncthreads();
    if (isLast && tid < BB) {
        __threadfence();                       // acquire others' atomicMax
        unsigned long long kb = atomicAdd(&best[tid], 0ull);  // coherent read
        unsigned int enc = (unsigned int)(kb >> 32);
        unsigned int ub  = (enc & 0x80000000u) ? (enc & 0x7fffffffu) : ~enc;
        float s  = __uint_as_float(ub);
        int idx  = 511 - (int)((kb >> 14) & 0x1FFu);
        int vv   = 16383 - (int)(kb & 0x3FFFu);
        int start = idx / EE;
        int e     = idx - start * EE;
        int end   = e + start + MINL - 1;
        out[tid]      = s;
        out[16 + tid] = (float)start;
        out[32 + tid] = (float)end;
        out[48 + tid] = (s > TH) ? 1.0f : 0.0f;
        out[64 + tid] = (float)vv;
    }
}

// ---------------------------------------------------------------------------
extern "C" void kernel_launch(void* const* d_in, const int* in_sizes, int n_in,
                              void* d_out, int out_size, void* d_ws, size_t ws_size,
                              hipStream_t stream) {
    const float* x       = (const float*)d_in[0];   // [16][64][60]
    const float* uf      = (const float*)d_in[1];   // [600][60]
    const float* W       = (const float*)d_in[2];   // [60][256]
    const int*   lengths = (const int*)d_in[3];     // [16]
    const int*   seg     = (const int*)d_in[4];     // [10000][10]
    const int*   vlen    = (const int*)d_in[5];     // [10000]
    float* out = (float*)d_out;
    float* ws  = (float*)d_ws;

    float*              unT  = ws + UNT_OFF;
    float*              wnT  = ws + WNT_OFF;
    float*              sim  = ws + SIM_OFF;
    unsigned int*       cnt  = (unsigned int*)(ws + CNT_OFF);
    unsigned int*       srt  = (unsigned int*)(ws + SRT_OFF);
    unsigned long long* best = (unsigned long long*)(ws + BEST_OFF);
    unsigned int*       done = (unsigned int*)(ws + DONE_OFF);

    // 3 dispatches: prep (sort+embed+zero atomics) -> sim -> score+final.
    k_prep<<<446, 256, 0, stream>>>(seg, vlen, x, uf, W, cnt, srt, unT, wnT,
                                    best, done);
    k_sim<<<512, 320, 0, stream>>>(unT, wnT, lengths, sim);
    k_score<<<512, 512, 0, stream>>>(sim, srt, cnt, lengths, best, done, out);
}

// Round 16
// 125.708 us; speedup vs baseline: 1.2909x; 1.0289x over previous
//
#include <hip/hip_runtime.h>
#include <math.h>

// Problem constants (from reference setup_inputs)
#define BB 16
#define LL 64
#define FF 60
#define DD 256
#define UU 600
#define VV 10000
#define JMAX 10
#define MINL 4
#define EE 7           // MAX_LEN - MIN_LEN + 1
#define NEG (-1e9f)
#define TH 0.05f
#define BCAP 10240     // per-bucket record capacity (>= V)

// Workspace layout in u32/float units (ws_size ~256 MB per harness fill — ample).
#define UNT_OFF   0                         // unT[256][640]  (u padded 600->640)
#define WNT_OFF   163840                    // wnT[256][1024] (bl = b*64+l)
#define SIM_OFF   425984                    // sim[16][64][600]
#define CNT_OFF   1040384                   // uint cnt[8] (written by k_prep blk 39)
#define SRT_OFF   1040392                   // records: 7 buckets x 10240 x 8 u32 (16B-aligned)
#define VAL_OFF   1613832                   // val[2][16][64][7]  (per v-half)
#define VOC_OFF   1628168                   // int voc[2][16][64][7]

// ---------------------------------------------------------------------------
// Fused prep: blocks [0,40) bucket-sort vocab records DETERMINISTICALLY
// (counting sort: pos(v) = #{v' < v with same vlen}); no atomics, bucket
// order = ascending v. Blocks [40,446) embed. Record (32B): w0..w4 = 10 x
// u16 LDS indices (u*13+j), w5 = v. Block 39 writes bucket totals to cnt[].
__global__ __launch_bounds__(256) void k_prep(const int* __restrict__ seg,
                                              const int* __restrict__ vlen,
                                              const float* __restrict__ x,
                                              const float* __restrict__ uf,
                                              const float* __restrict__ W,
                                              unsigned int* __restrict__ cnt,
                                              unsigned int* __restrict__ srt,
                                              float* __restrict__ unT,
                                              float* __restrict__ wnT) {
    __shared__ unsigned long long sP[4][2];  // per-wave packed prefix counts
    __shared__ int wTab[4][8];               // per-wave per-bucket counts (this block)
    __shared__ int sBase[8];                 // per-bucket counts below this block
    int blk = blockIdx.x;
    if (blk < 40) {
        int tid  = threadIdx.x;
        int lane = tid & 63;
        int w    = tid >> 6;
        int v    = blk * 256 + tid;

        // ---- prefix counts: scan vlen[0 .. blk*256), 16-bit packed lanes ----
        unsigned long long p0 = 0, p1 = 0;   // buckets 0-3 | 4-6, 16b fields
        int lim = blk * 256;
        for (int i = tid; i < lim; i += 256) {
            int e2 = vlen[i] - MINL;         // 0..6
            if (e2 < 4) p0 += 1ull << (e2 * 16);
            else        p1 += 1ull << ((e2 - 4) * 16);
        }
#pragma unroll
        for (int m = 32; m > 0; m >>= 1) {
            p0 += __shfl_xor(p0, m, 64);
            p1 += __shfl_xor(p1, m, 64);
        }
        if (lane == 0) { sP[w][0] = p0; sP[w][1] = p1; }

        // ---- own bucket + per-wave ballots (all lanes active; e=-1 invalid) ----
        int e = (v < VV) ? (vlen[v] - MINL) : -1;
        unsigned long long below = (lane == 0) ? 0ull : (~0ull >> (64 - lane));
        unsigned long long mym = 0;
#pragma unroll
        for (int b2 = 0; b2 < EE; ++b2) {
            unsigned long long m = __ballot(e == b2);
            if (lane == 0) wTab[w][b2] = (int)__popcll(m);
            if (e == b2) mym = m;
        }
        __syncthreads();
        if (tid < EE) {
            unsigned long long q0 = sP[0][0] + sP[1][0] + sP[2][0] + sP[3][0];
            unsigned long long q1 = sP[0][1] + sP[1][1] + sP[2][1] + sP[3][1];
            int base = (tid < 4) ? (int)((q0 >> (tid * 16)) & 0xffffull)
                                 : (int)((q1 >> ((tid - 4) * 16)) & 0xffffull);
            sBase[tid] = base;
            if (blk == 39)   // totals = prefix below blk 39 + blk 39's own
                cnt[tid] = (unsigned)(base + wTab[0][tid] + wTab[1][tid]
                                           + wTab[2][tid] + wTab[3][tid]);
        }
        __syncthreads();

        if (v < VV) {
            int prior = sBase[e];
#pragma unroll
            for (int w2 = 0; w2 < 4; ++w2) if (w2 < w) prior += wTab[w2][e];
            unsigned pos = (unsigned)(prior + (int)__popcll(mym & below));

            const int* s = seg + v * JMAX;
            unsigned int t[10];
#pragma unroll
            for (int j = 0; j < JMAX; ++j) t[j] = (unsigned int)(s[j] * 13 + j);
            unsigned int* dst = srt + ((size_t)e * BCAP + pos) * 8;
            uint4 qa, qb;
            qa.x = t[0] | (t[1] << 16);
            qa.y = t[2] | (t[3] << 16);
            qa.z = t[4] | (t[5] << 16);
            qa.w = t[6] | (t[7] << 16);
            qb.x = t[8] | (t[9] << 16);
            qb.y = (unsigned int)v;
            qb.z = 0; qb.w = 0;
            ((uint4*)dst)[0] = qa;
            ((uint4*)dst)[1] = qb;
        }
    } else {
        // embed: wave w of block handles row (blk-40)*4 + w; 1624 rows total.
        int w = threadIdx.x >> 6;
        int lane = threadIdx.x & 63;
        int id = (blk - 40) * 4 + w;
        const float* row;
        float* outB;
        int stride, col;
        if (id < UU) { row = uf + id * FF; outB = unT; stride = 640;  col = id; }
        else { int bl = id - UU; row = x + bl * FF; outB = wnT; stride = 1024; col = bl; }

        float r0 = 0.f, r1 = 0.f, r2 = 0.f, r3 = 0.f;
#pragma unroll 4
        for (int f = 0; f < FF; ++f) {
            float xv = row[f];  // wave-uniform broadcast load
            r0 += xv * W[f * DD + lane];
            r1 += xv * W[f * DD + lane + 64];
            r2 += xv * W[f * DD + lane + 128];
            r3 += xv * W[f * DD + lane + 192];
        }
        float ss = r0 * r0 + r1 * r1 + r2 * r2 + r3 * r3;
#pragma unroll
        for (int m = 32; m > 0; m >>= 1) ss += __shfl_xor(ss, m, 64);
        float inv = 1.0f / (sqrtf(ss) + 1e-8f);   // matches ref x/(norm+1e-8)
        outB[(lane      ) * stride + col] = r0 * inv;
        outB[(lane +  64) * stride + col] = r1 * inv;
        outB[(lane + 128) * stride + col] = r2 * inv;
        outB[(lane + 192) * stride + col] = r3 * inv;
    }
}

// ---------------------------------------------------------------------------
// sim[b][l][u] = wn[bl] . un[u].  512 blocks = (b, l-quad, u-half), 320
// threads. Thread tile: 4l x 1u; wn read as wave-uniform float4 per d.
__global__ __launch_bounds__(320) void k_sim(const float* __restrict__ unT,
                                             const float* __restrict__ wnT,
                                             const int* __restrict__ lengths,
                                             float* __restrict__ sim) {
    int blk = blockIdx.x;
    int b  = blk >> 5;
    int r  = blk & 31;
    int l0 = (r >> 1) * 4;
    if (l0 >= lengths[b]) return;       // rows beyond sentence length unused
    int uh = r & 1;
    int bl0 = b * 64 + l0;
    int u = uh * 320 + threadIdx.x;     // < 640 (unT padded; stores guarded)

    float a0 = 0.f, a1 = 0.f, a2 = 0.f, a3 = 0.f;
#pragma unroll 8
    for (int d = 0; d < DD; ++d) {
        float4 wv = *(const float4*)(wnT + d * 1024 + bl0);  // uniform 16B
        float v  = unT[d * 640 + u];
        a0 += wv.x * v;
        a1 += wv.y * v;
        a2 += wv.z * v;
        a3 += wv.w * v;
    }
    if (u < UU) {
        sim[(bl0 + 0) * UU + u] = a0;
        sim[(bl0 + 1) * UU + u] = a1;
        sim[(bl0 + 2) * UU + u] = a2;
        sim[(bl0 + 3) * UU + u] = a3;
    }
}

// ---------------------------------------------------------------------------
// Per-wave segment pass, STATIC K, 4 l-positions per record — r6 body
// verbatim. RAW-sum compare + min-v tie, winner normalized once at the
// reduce; ascending-v buckets keep ref's first-index tie semantics.
template<int K>
__device__ __forceinline__ void seg_pass4(const unsigned int* __restrict__ srt,
                                          const float* __restrict__ lds,
                                          int e, int r0, int r1, int lane, int wave,
                                          float (*redS)[8], int (*redV)[8]) {
    float s0 = -1e30f, s1 = -1e30f, s2 = -1e30f, s3 = -1e30f;
    int w0 = VV, w1 = VV, w2 = VV, w3 = VV;
    for (int p = r0 + lane; p < r1; p += 64) {
        const uint4* pp = (const uint4*)(srt + ((size_t)e * BCAP + p) * 8);
        uint4 qa = pp[0];
        uint4 qb = pp[1];
        unsigned int tw[5] = {qa.x, qa.y, qa.z, qa.w, qb.x};
        int v = (int)qb.y;
        float a0 = 0.f, a1 = 0.f, a2 = 0.f, a3 = 0.f;
#pragma unroll
        for (int j = 0; j < K; ++j) {
            int idx = (int)((tw[j >> 1] >> ((j & 1) * 16)) & 0xffffu);
            a0 += lds[idx];
            a1 += lds[idx + 1];
            a2 += lds[idx + 2];
            a3 += lds[idx + 3];
        }
        bool p0 = (a0 > s0) || (a0 == s0 && v < w0);
        bool p1 = (a1 > s1) || (a1 == s1 && v < w1);
        bool p2 = (a2 > s2) || (a2 == s2 && v < w2);
        bool p3 = (a3 > s3) || (a3 == s3 && v < w3);
        s0 = p0 ? a0 : s0;  w0 = p0 ? v : w0;
        s1 = p1 ? a1 : s1;  w1 = p1 ? v : w1;
        s2 = p2 ? a2 : s2;  w2 = p2 ? v : w2;
        s3 = p3 ? a3 : s3;  w3 = p3 ? v : w3;
    }
#pragma unroll
    for (int off = 32; off > 0; off >>= 1) {
        float os; int ov;
        os = __shfl_down(s0, off, 64); ov = __shfl_down(w0, off, 64);
        if (os > s0 || (os == s0 && ov < w0)) { s0 = os; w0 = ov; }
        os = __shfl_down(s1, off, 64); ov = __shfl_down(w1, off, 64);
        if (os > s1 || (os == s1 && ov < w1)) { s1 = os; w1 = ov; }
        os = __shfl_down(s2, off, 64); ov = __shfl_down(w2, off, 64);
        if (os > s2 || (os == s2 && ov < w2)) { s2 = os; w2 = ov; }
        os = __shfl_down(s3, off, 64); ov = __shfl_down(w3, off, 64);
        if (os > s3 || (os == s3 && ov < w3)) { s3 = os; w3 = ov; }
    }
    if (lane == 0) {
        redS[e * 4 + 0][wave] = s0; redV[e * 4 + 0][wave] = w0;
        redS[e * 4 + 1][wave] = s1; redV[e * 4 + 1][wave] = w1;
        redS[e * 4 + 2][wave] = s2; redV[e * 4 + 2][wave] = w2;
        redS[e * 4 + 3][wave] = s3; redV[e * 4 + 3][wave] = w3;
    }
}

// ---------------------------------------------------------------------------
// Phase 3: 512 blocks = (v-half, b, l-quad), 512 threads. float4-vectorized
// staging (r11 win) + __launch_bounds__(512,2) (VGPR slack; occupancy is
// grid/LDS-limited regardless). This exact kernel benched 125.93us (r11) —
// the session best. r15's k_final fusion regressed (done-counter drain ==
// dispatch cost); reverted.
__global__ __launch_bounds__(512, 2) void k_score(const float* __restrict__ sim,
                                                  const unsigned int* __restrict__ srt,
                                                  const unsigned int* __restrict__ cnt,
                                                  const int* __restrict__ lengths,
                                                  float* __restrict__ val,
                                                  int* __restrict__ voc) {
    __shared__ float lds[UU * 13];   // 31.2 KB
    __shared__ float redS[28][8];    // [e*4+dl][wave]
    __shared__ int   redV[28][8];

    int blk = blockIdx.x;
    int half = blk >> 8;
    int rest = blk & 255;
    int b  = rest >> 4;
    int l0 = (rest & 15) * 4;
    int tid = threadIdx.x;
    int len = lengths[b];            // uniform scalar load

    if (l0 + MINL - 1 >= len) {      // no bucket active for this quad
        if (tid < 28) {
            int e  = tid >> 2;
            int dl = tid & 3;
            int o = (half * BB * LL + b * 64 + l0 + dl) * EE + e;
            val[o] = NEG;
            voc[o] = 0;
        }
        return;                       // block-uniform: no barrier hazards
    }

    if (tid < 224) {                 // init all 28x8 reduction slots
        redS[tid >> 3][tid & 7] = -1e30f;
        redV[tid >> 3][tid & 7] = VV;
    }
    // Stage sim tile -> LDS transposed, float4-vectorized: 13 rows x 150
    // float4 chunks; (b*64+m)*600 + 4c is 16B-aligned (600 % 4 == 0).
    for (int i = tid; i < 13 * 150; i += 512) {
        int r = i / 150;
        int c = i - r * 150;
        int m = l0 + r;
        float4 v4;
        if (m < LL) v4 = *(const float4*)(sim + (size_t)(b * 64 + m) * UU + 4 * c);
        else        v4 = make_float4(0.f, 0.f, 0.f, 0.f);
        int u0 = 4 * c;
        lds[(u0 + 0) * 13 + r] = v4.x;
        lds[(u0 + 1) * 13 + r] = v4.y;
        lds[(u0 + 2) * 13 + r] = v4.z;
        lds[(u0 + 3) * 13 + r] = v4.w;
    }
    __syncthreads();

    int wave = tid >> 6, lane = tid & 63;

    // Work-proportional wave slicing over this half's ACTIVE buckets.
    unsigned nlo[EE], nhi[EE], Bw[EE];
    unsigned Wtot = 0;
#pragma unroll
    for (int e = 0; e < EE; ++e) {
        unsigned n = cnt[e];
        unsigned lo = half ? (n >> 1) : 0;
        unsigned hi = half ? n : (n >> 1);
        if (l0 + e + MINL - 1 >= len) { lo = 0; hi = 0; }  // bucket dead for whole quad
        nlo[e] = lo; nhi[e] = hi;
        Bw[e] = Wtot;
        Wtot += (hi - lo) * (unsigned)(e + MINL);
    }
    unsigned qlo = (unsigned)(((unsigned long long)Wtot * (unsigned)wave) >> 3);
    unsigned qhi = (unsigned)(((unsigned long long)Wtot * (unsigned)(wave + 1)) >> 3);

#pragma unroll
    for (int e = 0; e < EE; ++e) {
        unsigned K = (unsigned)(e + MINL);
        unsigned segw = (nhi[e] - nlo[e]) * K;
        unsigned Be = Bw[e];
        if (qhi <= Be || qlo >= Be + segw || segw == 0) continue;
        unsigned a = (qlo > Be) ? (qlo - Be) : 0;
        unsigned bb = qhi - Be; if (bb > segw) bb = segw;
        int r0 = (int)(nlo[e] + (a + K - 1) / K);
        int r1 = (int)(nlo[e] + (bb + K - 1) / K);
        if (r1 <= r0) continue;
        switch (e) {   // wave-uniform branch
            case 0: seg_pass4<4> (srt, lds, 0, r0, r1, lane, wave, redS, redV); break;
            case 1: seg_pass4<5> (srt, lds, 1, r0, r1, lane, wave, redS, redV); break;
            case 2: seg_pass4<6> (srt, lds, 2, r0, r1, lane, wave, redS, redV); break;
            case 3: seg_pass4<7> (srt, lds, 3, r0, r1, lane, wave, redS, redV); break;
            case 4: seg_pass4<8> (srt, lds, 4, r0, r1, lane, wave, redS, redV); break;
            case 5: seg_pass4<9> (srt, lds, 5, r0, r1, lane, wave, redS, redV); break;
            case 6: seg_pass4<10>(srt, lds, 6, r0, r1, lane, wave, redS, redV); break;
        }
    }
    __syncthreads();

    if (tid < 28) {   // reduce 8 wave-slots per (e, dl); normalize winner only
        int e  = tid >> 2;
        int dl = tid & 3;
        float s = redS[tid][0];
        int  vv = redV[tid][0];
#pragma unroll
        for (int w2 = 1; w2 < 8; ++w2) {
            float os = redS[tid][w2];
            int   ov = redV[tid][w2];
            if (os > s || (os == s && ov < vv)) { s = os; vv = ov; }
        }
        int lg = l0 + dl;
        int k = e + MINL;
        bool viable = (lg + k - 1) < len;
        float sn = s / (float)k;   // bit-same as ref a/k for the winner
        int o = (half * BB * LL + b * 64 + lg) * EE + e;
        val[o] = viable ? sn : NEG;
        voc[o] = viable ? vv : 0;  // ref argmax of all-NEG = 0
    }
}

// ---------------------------------------------------------------------------
// Per-b: merge the two v-halves slot-wise (tie -> smaller voc = smaller v),
// then flat argmax over the 448 (l,e) slots (min flat index on ties),
// any_matched = merged max > THRESH. Outputs written as float32 values.
__global__ __launch_bounds__(512) void k_final(const float* __restrict__ val,
                                               const int* __restrict__ voc,
                                               float* __restrict__ out) {
    __shared__ float sS[8];
    __shared__ int   sI[8];
    __shared__ int   sV[8];
    __shared__ int   sA[8];
    int b = blockIdx.x;
    int t = threadIdx.x;
    float s = -3e38f;
    int idx = 1 << 30;
    int vc = 0;
    int any = 0;
    if (t < LL * EE) {
        int o0 = b * LL * EE + t;
        int o1 = BB * LL * EE + o0;
        float s0 = val[o0], s1 = val[o1];
        int   v0 = voc[o0], v1 = voc[o1];
        bool sel = (s1 > s0) || (s1 == s0 && v1 < v0);
        s  = sel ? s1 : s0;
        vc = sel ? v1 : v0;
        idx = t;
        any = (s > TH) ? 1 : 0;
    }
#pragma unroll
    for (int off = 32; off > 0; off >>= 1) {
        float os = __shfl_down(s, off, 64);
        int   oi = __shfl_down(idx, off, 64);
        int   ov = __shfl_down(vc, off, 64);
        int   oa = __shfl_down(any, off, 64);
        if (os > s || (os == s && oi < idx)) { s = os; idx = oi; vc = ov; }
        any |= oa;
    }
    int w = t >> 6, lane = t & 63;
    if (lane == 0) { sS[w] = s; sI[w] = idx; sV[w] = vc; sA[w] = any; }
    __syncthreads();
    if (t == 0) {
        for (int w2 = 1; w2 < 8; ++w2) {
            float os = sS[w2];
            int   oi = sI[w2];
            if (os > s || (os == s && oi < idx)) { s = os; idx = oi; vc = sV[w2]; }
            any |= sA[w2];
        }
        int start = idx / EE;
        int e = idx - start * EE;
        int end = e + start + MINL - 1;
        out[b]      = s;
        out[16 + b] = (float)start;
        out[32 + b] = (float)end;
        out[48 + b] = any ? 1.0f : 0.0f;
        out[64 + b] = (float)vc;
    }
}

// ---------------------------------------------------------------------------
extern "C" void kernel_launch(void* const* d_in, const int* in_sizes, int n_in,
                              void* d_out, int out_size, void* d_ws, size_t ws_size,
                              hipStream_t stream) {
    const float* x       = (const float*)d_in[0];   // [16][64][60]
    const float* uf      = (const float*)d_in[1];   // [600][60]
    const float* W       = (const float*)d_in[2];   // [60][256]
    const int*   lengths = (const int*)d_in[3];     // [16]
    const int*   seg     = (const int*)d_in[4];     // [10000][10]
    const int*   vlen    = (const int*)d_in[5];     // [10000]
    float* out = (float*)d_out;
    float* ws  = (float*)d_ws;

    float*        unT = ws + UNT_OFF;
    float*        wnT = ws + WNT_OFF;
    float*        sim = ws + SIM_OFF;
    unsigned int* cnt = (unsigned int*)(ws + CNT_OFF);
    unsigned int* srt = (unsigned int*)(ws + SRT_OFF);
    float*        val = ws + VAL_OFF;
    int*          voc = (int*)(ws + VOC_OFF);

    // No memset: k_prep's counting sort is atomic-free and writes cnt totals.
    k_prep<<<446, 256, 0, stream>>>(seg, vlen, x, uf, W, cnt, srt, unT, wnT);
    k_sim<<<512, 320, 0, stream>>>(unT, wnT, lengths, sim);
    k_score<<<512, 512, 0, stream>>>(sim, srt, cnt, lengths, val, voc);
    k_final<<<BB, 512, 0, stream>>>(val, voc, out);
}